// Round 3
// baseline (66.255 us; speedup 1.0000x reference)
//
#include <hip/hip_runtime.h>

// RNNFFT: depth-10 radix-2 butterfly network over last dim (1024).
// v = x; for l = 9..0: y = B_l(w_l * v); v = (l==1) ? y : x + y
// Pairs at level l: (e, e^h), h = 512>>l. Twiddle: bw[OFF[l] + (e & (n_l-1))].
// Mix (einsum 'ij,...ik->...jk' => lw^T): role-j: y = lw[j][j]*t_self + lw[1-j][j]*t_partner.
// One wave handles NV=2 vectors, 16 elems/lane each (e = lane*16 + r):
//   levels 6..9 (h=8,4,2,1): in-register pairs (r, r^h), twiddles are lane-uniform (SGPR)
//   levels 0..5 (h=512..16): __shfl_xor with mask 32>>l; per-lane twiddles double-buffered
//     and prefetched one level ahead so vmcnt waits overlap compute.

constexpr int VECLEN = 1024;
constexpr int NV = 2;  // vectors per wave

template<int L>
__device__ __forceinline__ void loadw(float (&w)[16], const float* __restrict__ bw, int lane) {
  constexpr int n = VECLEN >> L;
  constexpr int off = 2048 - (2048 >> L);  // OFFSETS[L]
  const int wbase = off + ((lane * 16) & (n - 1));
#pragma unroll
  for (int k = 0; k < 4; ++k) {
    const float4 f = *reinterpret_cast<const float4*>(bw + wbase + 4 * k);
    w[4 * k + 0] = f.x; w[4 * k + 1] = f.y; w[4 * k + 2] = f.z; w[4 * k + 3] = f.w;
  }
}

template<int L, bool RESL>
__device__ __forceinline__ void level_inlane(float (&v)[NV][16], const float (&xr)[NV][16],
                                             const float* __restrict__ bw,
                                             const float* __restrict__ lw) {
  constexpr int n = VECLEN >> L;          // 16, 8, 4, 2
  constexpr int h = n >> 1;               // 8, 4, 2, 1
  constexpr int off = 2048 - (2048 >> L); // OFFSETS[L]
  float w[n];                              // lane-uniform -> scalar loads
#pragma unroll
  for (int i = 0; i < n; ++i) w[i] = bw[off + i];
  const float l00 = lw[L * 4 + 0], l01 = lw[L * 4 + 1];
  const float l10 = lw[L * 4 + 2], l11 = lw[L * 4 + 3];
#pragma unroll
  for (int u = 0; u < NV; ++u) {
#pragma unroll
    for (int r = 0; r < 16; ++r) {
      if ((r & h) == 0) {
        const int q = r ^ h;
        const float t0 = w[r & (n - 1)] * v[u][r];
        const float t1 = w[q & (n - 1)] * v[u][q];
        const float y0 = l00 * t0 + l10 * t1;   // role 0
        const float y1 = l01 * t0 + l11 * t1;   // role 1
        v[u][r] = RESL ? xr[u][r] + y0 : y0;
        v[u][q] = RESL ? xr[u][q] + y1 : y1;
      }
    }
  }
}

template<int L, bool RESL>
__device__ __forceinline__ void level_cross(float (&v)[NV][16], const float (&xr)[NV][16],
                                            const float (&w)[16],
                                            const float* __restrict__ lw, int lane) {
  constexpr int mask = 32 >> L;           // shfl_xor lane mask
  const int role = (lane >> (5 - L)) & 1;
  const float l00 = lw[L * 4 + 0], l01 = lw[L * 4 + 1];
  const float l10 = lw[L * 4 + 2], l11 = lw[L * 4 + 3];
  const float cs = role ? l11 : l00;      // coeff on own t
  const float cp = role ? l01 : l10;      // coeff on partner t
#pragma unroll
  for (int u = 0; u < NV; ++u) {
#pragma unroll
    for (int r = 0; r < 16; ++r) {
      const float t = w[r] * v[u][r];
      const float tp = __shfl_xor(t, mask, 64);
      const float y = cs * t + cp * tp;
      v[u][r] = RESL ? xr[u][r] + y : y;
    }
  }
}

__global__ __launch_bounds__(256, 4) void rnnfft_kernel(const float* __restrict__ x,
                                                        const float* __restrict__ bw,
                                                        const float* __restrict__ lw,
                                                        float* __restrict__ out, int nvec) {
  const int wid = blockIdx.x * 4 + (threadIdx.x >> 6);   // wave id
  const int lane = threadIdx.x & 63;
  if (wid * NV >= nvec) return;
  const size_t base = (size_t)wid * (VECLEN * NV) + lane * 16;

  float v[NV][16], xr[NV][16];
  // Issue all x loads (8 independent dwordx4) up front.
#pragma unroll
  for (int u = 0; u < NV; ++u) {
#pragma unroll
    for (int k = 0; k < 4; ++k) {
      const float4 f = *reinterpret_cast<const float4*>(x + base + u * VECLEN + 4 * k);
      xr[u][4 * k + 0] = f.x; xr[u][4 * k + 1] = f.y;
      xr[u][4 * k + 2] = f.z; xr[u][4 * k + 3] = f.w;
    }
  }

  // Prefetch twiddles for the first two cross levels while in-lane levels run.
  float wA[16], wB[16];
  loadw<5>(wA, bw, lane);
  loadw<4>(wB, bw, lane);

#pragma unroll
  for (int u = 0; u < NV; ++u)
#pragma unroll
    for (int r = 0; r < 16; ++r) v[u][r] = xr[u][r];

  // Deepest level first (adjacent pairs), unwinding to level 0 (halves).
  level_inlane<9, true >(v, xr, bw, lw);
  level_inlane<8, true >(v, xr, bw, lw);
  level_inlane<7, true >(v, xr, bw, lw);
  level_inlane<6, true >(v, xr, bw, lw);

  level_cross<5, true >(v, xr, wA, lw, lane);
  loadw<3>(wA, bw, lane);
  level_cross<4, true >(v, xr, wB, lw, lane);
  loadw<2>(wB, bw, lane);
  level_cross<3, true >(v, xr, wA, lw, lane);
  loadw<1>(wA, bw, lane);
  level_cross<2, true >(v, xr, wB, lw, lane);
  loadw<0>(wB, bw, lane);
  level_cross<1, false>(v, xr, wA, lw, lane);  // RES[1] = False
  level_cross<0, true >(v, xr, wB, lw, lane);

#pragma unroll
  for (int u = 0; u < NV; ++u) {
#pragma unroll
    for (int k = 0; k < 4; ++k) {
      float4 f;
      f.x = v[u][4 * k + 0]; f.y = v[u][4 * k + 1];
      f.z = v[u][4 * k + 2]; f.w = v[u][4 * k + 3];
      *reinterpret_cast<float4*>(out + base + u * VECLEN + 4 * k) = f;
    }
  }
}

extern "C" void kernel_launch(void* const* d_in, const int* in_sizes, int n_in,
                              void* d_out, int out_size, void* d_ws, size_t ws_size,
                              hipStream_t stream) {
  const float* x  = (const float*)d_in[0];
  const float* bw = (const float*)d_in[1];
  const float* lw = (const float*)d_in[2];
  float* out = (float*)d_out;
  const int nvec = in_sizes[0] / VECLEN;        // 16384 vectors
  const int nwave = nvec / NV;                  // 8192 waves
  const int wpb = 4;                            // waves per block (256 threads)
  const int blocks = (nwave + wpb - 1) / wpb;
  rnnfft_kernel<<<blocks, 256, 0, stream>>>(x, bw, lw, out, nvec);
}

// Round 4
// 44.405 us; speedup vs baseline: 1.4920x; 1.4920x over previous
//
#include <hip/hip_runtime.h>

// RNNFFT: depth-10 radix-2 butterfly network over last dim (1024).
// v = x; for l = 9..0: y = B_l(w_l * v); v = (l==1) ? y : x + y
// Pairs at level l: (e, e^h), h = 512>>l. Twiddle: bw[OFF[l] + (e & (n_l-1))].
// Mix (einsum 'ij,...ik->...jk' => lw^T): role-j: y = lw[j][j]*t_self + lw[1-j][j]*t_partner.
// One wave per vector, 16 elems/lane (e = lane*16 + r):
//   levels 6..9 (h=8,4,2,1): in-register pairs (r, r^h), twiddles lane-uniform (SGPR loads)
//   levels 0..5 (h=512..16): __shfl_xor with mask 32>>l; per-lane twiddles double-buffered
//     and prefetched one level ahead so vmcnt waits overlap shuffle/FMA work.
//
// R3 post-mortem: NV=2 + launch_bounds(256,4) made the allocator spill the whole
// xr[] residual array to scratch (+125 MB writes). NV=1 live set ~90 regs; the
// amdgpu_waves_per_eu(2,4) cap tells the allocator occupancy >4/EU is worthless,
// so it can use up to 128 VGPRs without spilling OR re-loading x from cache.

constexpr int VECLEN = 1024;

template<int L>
__device__ __forceinline__ void loadw(float (&w)[16], const float* __restrict__ bw, int lane) {
  constexpr int n = VECLEN >> L;
  constexpr int off = 2048 - (2048 >> L);  // OFFSETS[L]
  const int wbase = off + ((lane * 16) & (n - 1));
#pragma unroll
  for (int k = 0; k < 4; ++k) {
    const float4 f = *reinterpret_cast<const float4*>(bw + wbase + 4 * k);
    w[4 * k + 0] = f.x; w[4 * k + 1] = f.y; w[4 * k + 2] = f.z; w[4 * k + 3] = f.w;
  }
}

template<int L, bool RESL>
__device__ __forceinline__ void level_inlane(float (&v)[16], const float (&xr)[16],
                                             const float* __restrict__ bw,
                                             const float* __restrict__ lw) {
  constexpr int n = VECLEN >> L;          // 16, 8, 4, 2
  constexpr int h = n >> 1;               // 8, 4, 2, 1
  constexpr int off = 2048 - (2048 >> L); // OFFSETS[L]
  float w[n];                              // lane-uniform -> scalar (SGPR) loads
#pragma unroll
  for (int i = 0; i < n; ++i) w[i] = bw[off + i];
  const float l00 = lw[L * 4 + 0], l01 = lw[L * 4 + 1];
  const float l10 = lw[L * 4 + 2], l11 = lw[L * 4 + 3];
#pragma unroll
  for (int r = 0; r < 16; ++r) {
    if ((r & h) == 0) {
      const int q = r ^ h;
      const float t0 = w[r & (n - 1)] * v[r];
      const float t1 = w[q & (n - 1)] * v[q];
      const float y0 = l00 * t0 + l10 * t1;   // role 0
      const float y1 = l01 * t0 + l11 * t1;   // role 1
      v[r] = RESL ? xr[r] + y0 : y0;
      v[q] = RESL ? xr[q] + y1 : y1;
    }
  }
}

template<int L, bool RESL>
__device__ __forceinline__ void level_cross(float (&v)[16], const float (&xr)[16],
                                            const float (&w)[16],
                                            const float* __restrict__ lw, int lane) {
  constexpr int mask = 32 >> L;           // shfl_xor lane mask
  const int role = (lane >> (5 - L)) & 1;
  const float l00 = lw[L * 4 + 0], l01 = lw[L * 4 + 1];
  const float l10 = lw[L * 4 + 2], l11 = lw[L * 4 + 3];
  const float cs = role ? l11 : l00;      // coeff on own t
  const float cp = role ? l01 : l10;      // coeff on partner t
#pragma unroll
  for (int r = 0; r < 16; ++r) {
    const float t = w[r] * v[r];
    const float tp = __shfl_xor(t, mask, 64);
    const float y = cs * t + cp * tp;
    v[r] = RESL ? xr[r] + y : y;
  }
}

__global__ __launch_bounds__(256)
__attribute__((amdgpu_waves_per_eu(2, 4)))
void rnnfft_kernel(const float* __restrict__ x,
                   const float* __restrict__ bw,
                   const float* __restrict__ lw,
                   float* __restrict__ out, int nvec) {
  const int wid = blockIdx.x * 4 + (threadIdx.x >> 6);   // wave id = vector id
  const int lane = threadIdx.x & 63;
  if (wid >= nvec) return;
  const size_t base = (size_t)wid * VECLEN + lane * 16;

  float v[16], xr[16];
  // Issue all 4 x-loads (independent dwordx4) up front.
#pragma unroll
  for (int k = 0; k < 4; ++k) {
    const float4 f = *reinterpret_cast<const float4*>(x + base + 4 * k);
    xr[4 * k + 0] = f.x; xr[4 * k + 1] = f.y;
    xr[4 * k + 2] = f.z; xr[4 * k + 3] = f.w;
  }

  // Prefetch twiddles for the first two cross levels; they land while the
  // in-lane levels compute.
  float wA[16], wB[16];
  loadw<5>(wA, bw, lane);
  loadw<4>(wB, bw, lane);

#pragma unroll
  for (int r = 0; r < 16; ++r) v[r] = xr[r];

  // Deepest level first (adjacent pairs), unwinding to level 0 (halves).
  level_inlane<9, true >(v, xr, bw, lw);
  level_inlane<8, true >(v, xr, bw, lw);
  level_inlane<7, true >(v, xr, bw, lw);
  level_inlane<6, true >(v, xr, bw, lw);

  level_cross<5, true >(v, xr, wA, lw, lane);
  loadw<3>(wA, bw, lane);
  level_cross<4, true >(v, xr, wB, lw, lane);
  loadw<2>(wB, bw, lane);
  level_cross<3, true >(v, xr, wA, lw, lane);
  loadw<1>(wA, bw, lane);
  level_cross<2, true >(v, xr, wB, lw, lane);
  loadw<0>(wB, bw, lane);
  level_cross<1, false>(v, xr, wA, lw, lane);  // RES[1] = False
  level_cross<0, true >(v, xr, wB, lw, lane);

#pragma unroll
  for (int k = 0; k < 4; ++k) {
    float4 f;
    f.x = v[4 * k + 0]; f.y = v[4 * k + 1];
    f.z = v[4 * k + 2]; f.w = v[4 * k + 3];
    *reinterpret_cast<float4*>(out + base + 4 * k) = f;
  }
}

extern "C" void kernel_launch(void* const* d_in, const int* in_sizes, int n_in,
                              void* d_out, int out_size, void* d_ws, size_t ws_size,
                              hipStream_t stream) {
  const float* x  = (const float*)d_in[0];
  const float* bw = (const float*)d_in[1];
  const float* lw = (const float*)d_in[2];
  float* out = (float*)d_out;
  const int nvec = in_sizes[0] / VECLEN;        // 16384 vectors
  const int wpb = 4;                            // waves per block (256 threads)
  const int blocks = (nvec + wpb - 1) / wpb;
  rnnfft_kernel<<<blocks, 256, 0, stream>>>(x, bw, lw, out, nvec);
}